// Round 1
// baseline (296.920 us; speedup 1.0000x reference)
//
#include <hip/hip_runtime.h>
#include <cmath>

// Problem constants from the reference: x is (16, 1, 1536, 1536) float32.
#define B_ 16
#define H_ 1536
#define W_ 1536

// One block per (batch, row). 384 threads (= 6 waves), each handling one
// float4 (4 consecutive w). Stencil needs rows h, h-1, h-2 (wrap) and
// columns w-1, w-2 (wrap).
//
// NOTE on numerics: the reference's remove_nan semantics make the output
// discontinuous where Hc^2 ~= Kc (root -> NaN -> 0 vs root -> tiny -> +-1).
// We therefore replicate the reference's exact f32 operation association and
// disable FMA contraction so our rounding matches a numpy f32 reference.
__global__ __launch_bounds__(384) void ShapeIndex_kernel(
        const float* __restrict__ x, float* __restrict__ out) {
#pragma clang fp contract(off)
    const int h  = blockIdx.x;       // 0..1535
    const int b  = blockIdx.y;       // 0..15
    const int w4 = threadIdx.x;      // 0..383
    const int w  = w4 * 4;

    const float* plane = x + (size_t)b * (H_ * W_);
    const int hm1 = (h == 0) ? (H_ - 1) : (h - 1);
    const int hm2 = (h <= 1) ? (h + H_ - 2) : (h - 2);

    const float4 vc = *(const float4*)(plane + h   * W_ + w);  // x[h][w..w+3]
    const float4 v1 = *(const float4*)(plane + hm1 * W_ + w);  // x[h-1][w..w+3]
    const float4 v2 = *(const float4*)(plane + hm2 * W_ + w);  // x[h-2][w..w+3]

    const int wm1 = (w == 0) ? (W_ - 1) : (w - 1);
    const int wm2 = (w == 0) ? (W_ - 2) : (w - 2);
    const float L0  = plane[h   * W_ + wm1];  // x[h][w-1]
    const float L1  = plane[h   * W_ + wm2];  // x[h][w-2]
    const float Lh1 = plane[hm1 * W_ + wm1];  // x[h-1][w-1]

    float c [4] = {vc.x, vc.y, vc.z, vc.w};
    float a1[4] = {v1.x, v1.y, v1.z, v1.w};
    float a2[4] = {v2.x, v2.y, v2.z, v2.w};
    float res[4];

#pragma unroll
    for (int j = 0; j < 4; ++j) {
        const float xc    = c[j];                                   // x[h][wj]
        const float xh1   = a1[j];                                  // x[h-1][wj]
        const float xh2   = a2[j];                                  // x[h-2][wj]
        const float xw1   = (j > 0) ? c[j-1]  : L0;                 // x[h][wj-1]
        const float xw2   = (j > 1) ? c[j-2]  : ((j == 1) ? L0 : L1); // x[h][wj-2]
        const float xh1w1 = (j > 0) ? a1[j-1] : Lh1;                // x[h-1][wj-1]

        // grad(m, ax) = roll(m,1,ax) - m, each a single f32 subtraction,
        // matching the reference's evaluation order exactly.
        const float p    = xh1   - xc;    // p[h][wj]
        const float q    = xw1   - xc;    // q[h][wj]
        const float p_up = xh2   - xh1;   // p[h-1][wj]
        const float p_lf = xh1w1 - xw1;   // p[h][wj-1]
        const float q_lf = xw2   - xw1;   // q[h][wj-1]
        const float r = p_up - p;
        const float s = p_lf - p;
        const float t = q_lf - q;

        const float pp = p * p;
        const float qq = q * q;
        const float one_pq = (1.0f + pp) + qq;          // (1.0 + p*p) + q*q

        // ((1+q*q)*r - 2.0*p*q*s) + (1+p*p)*t, left-to-right like Python
        const float A = ((1.0f + qq) * r - ((2.0f * p) * q) * s)
                        + (1.0f + pp) * t;
        const float cube = (one_pq * one_pq) * one_pq;  // one_pq ** 3
        float Hc = -(A / (2.0f * sqrtf(cube)));
        if (Hc != Hc) Hc = 0.0f;                        // remove_nan

        const float sq = one_pq * one_pq;               // one_pq ** 2
        float Kc = (r * t - s * s) / sq;
        if (Kc != Kc) Kc = 0.0f;                        // remove_nan

        const float root = sqrtf(Hc * Hc - Kc);         // NaN if Hc^2 < Kc
        float kmin = Hc - root; if (kmin != kmin) kmin = 0.0f;
        float kmax = Hc + root; if (kmax != kmax) kmax = 0.0f;

        // IEEE division: x/0 -> inf (atan -> +-pi/2 -> si = +-1), 0/0 -> NaN.
        float si = 0.63661977236758134f * atanf((kmax + kmin) / (kmax - kmin));
        if (si != si) si = 0.0f;                        // remove_nan
        res[j] = si;
    }

    *(float4*)(out + (size_t)b * (H_ * W_) + h * W_ + w) =
        make_float4(res[0], res[1], res[2], res[3]);
}

extern "C" void kernel_launch(void* const* d_in, const int* in_sizes, int n_in,
                              void* d_out, int out_size, void* d_ws, size_t ws_size,
                              hipStream_t stream) {
    const float* x = (const float*)d_in[0];
    float* out = (float*)d_out;
    dim3 grid(H_, B_);
    dim3 block(384);
    ShapeIndex_kernel<<<grid, block, 0, stream>>>(x, out);
}

// Round 2
// 284.016 us; speedup vs baseline: 1.0454x; 1.0454x over previous
//
#include <hip/hip_runtime.h>
#include <cmath>

// Problem constants from the reference: x is (16, 1, 1536, 1536) float32.
#define B_ 16
#define H_ 1536
#define W_ 1536

// Fast atan accurate to ~1e-5 rad (absolute). Must preserve:
//   atan(+-inf) -> +-pi/2 (exactly, via rcp(inf)=0)
//   atan(NaN)   -> NaN    (NaN>1 is false -> poly(NaN) -> NaN)
// Explicit FMA is used (contract-off pragma does not apply to __builtin_fmaf).
__device__ __forceinline__ float fast_atan(float z) {
    const float az  = fabsf(z);
    const float inv = __builtin_amdgcn_rcpf(az);   // v_rcp_f32, ~1 ulp
    const bool  big = az > 1.0f;
    const float u   = big ? inv : az;
    const float x2  = u * u;
    // degree-11 odd minimax on [0,1], max abs err ~1e-5
    float p = __builtin_fmaf(x2, -0.01172120f, 0.05265332f);
    p = __builtin_fmaf(x2, p, -0.11643287f);
    p = __builtin_fmaf(x2, p,  0.19354346f);
    p = __builtin_fmaf(x2, p, -0.33262347f);
    p = __builtin_fmaf(x2, p,  0.99997726f);
    const float a   = u * p;
    const float res = big ? (1.57079632679489662f - a) : a;
    return copysignf(res, z);
}

// One block per (batch, row). 384 threads (= 6 waves), each handling one
// float4 (4 consecutive w). Stencil needs rows h, h-1, h-2 (wrap) and
// columns w-1, w-2 (wrap).
//
// NUMERICS: everything up to kmin/kmax must stay bitwise identical to the
// numpy f32 reference (exact association, IEEE div/sqrt, no contraction) --
// the discriminant Hc^2-Kc is analytically >=0 and its rounding-determined
// sign selects between si=0 (NaN path) and si=+-1, a 1.0 jump. Only the
// final divide (num*rcp, same inf/NaN semantics) and atan (smooth or
// saturating in z) tolerate approximation.
__global__ __launch_bounds__(384) void ShapeIndex_kernel(
        const float* __restrict__ x, float* __restrict__ out) {
#pragma clang fp contract(off)
    const int h  = blockIdx.x;       // 0..1535
    const int b  = blockIdx.y;       // 0..15
    const int w  = threadIdx.x * 4;

    const float* plane = x + (size_t)b * (H_ * W_);
    const int hm1 = (h == 0) ? (H_ - 1) : (h - 1);
    const int hm2 = (h <= 1) ? (h + H_ - 2) : (h - 2);

    const float4 vc = *(const float4*)(plane + h   * W_ + w);  // x[h][w..w+3]
    const float4 v1 = *(const float4*)(plane + hm1 * W_ + w);  // x[h-1][w..w+3]
    const float4 v2 = *(const float4*)(plane + hm2 * W_ + w);  // x[h-2][w..w+3]

    const int wm1 = (w == 0) ? (W_ - 1) : (w - 1);
    const int wm2 = (w == 0) ? (W_ - 2) : (w - 2);
    const float L0  = plane[h   * W_ + wm1];  // x[h][w-1]
    const float L1  = plane[h   * W_ + wm2];  // x[h][w-2]
    const float Lh1 = plane[hm1 * W_ + wm1];  // x[h-1][w-1]

    float c [4] = {vc.x, vc.y, vc.z, vc.w};
    float a1[4] = {v1.x, v1.y, v1.z, v1.w};
    float a2[4] = {v2.x, v2.y, v2.z, v2.w};
    float res[4];

#pragma unroll
    for (int j = 0; j < 4; ++j) {
        const float xc    = c[j];                                   // x[h][wj]
        const float xh1   = a1[j];                                  // x[h-1][wj]
        const float xh2   = a2[j];                                  // x[h-2][wj]
        const float xw1   = (j > 0) ? c[j-1]  : L0;                 // x[h][wj-1]
        const float xw2   = (j > 1) ? c[j-2]  : ((j == 1) ? L0 : L1); // x[h][wj-2]
        const float xh1w1 = (j > 0) ? a1[j-1] : Lh1;                // x[h-1][wj-1]

        // grad(m, ax) = roll(m,1,ax) - m, single f32 subs, reference order.
        const float p    = xh1   - xc;    // p[h][wj]
        const float q    = xw1   - xc;    // q[h][wj]
        const float p_up = xh2   - xh1;   // p[h-1][wj]
        const float p_lf = xh1w1 - xw1;   // p[h][wj-1]
        const float q_lf = xw2   - xw1;   // q[h][wj-1]
        const float r = p_up - p;
        const float s = p_lf - p;
        const float t = q_lf - q;

        const float pp = p * p;
        const float qq = q * q;
        const float one_pq = (1.0f + pp) + qq;          // (1.0 + p*p) + q*q

        // ((1+q*q)*r - 2.0*p*q*s) + (1+p*p)*t, left-to-right like Python
        const float A = ((1.0f + qq) * r - ((2.0f * p) * q) * s)
                        + (1.0f + pp) * t;
        const float cube = (one_pq * one_pq) * one_pq;  // one_pq ** 3 (x2*x)
        float Hc = -(A / (2.0f * sqrtf(cube)));         // IEEE div+sqrt: exact
        if (Hc != Hc) Hc = 0.0f;                        // remove_nan

        const float sq = one_pq * one_pq;               // one_pq ** 2
        float Kc = (r * t - s * s) / sq;                // IEEE div: exact
        if (Kc != Kc) Kc = 0.0f;                        // remove_nan

        const float root = sqrtf(Hc * Hc - Kc);         // NaN if disc < 0
        float kmin = Hc - root; if (kmin != kmin) kmin = 0.0f;
        float kmax = Hc + root; if (kmax != kmax) kmax = 0.0f;

        // z = num/den via num*rcp(den): den=0 -> num*inf = +-inf (num!=0)
        // or NaN (num==0); den=NaN -> NaN. Matches IEEE div special cases;
        // finite-case error ~2 ulp lands in atan's smooth/saturating region.
        const float num = kmax + kmin;
        const float den = kmax - kmin;
        const float z   = num * __builtin_amdgcn_rcpf(den);
        float si = 0.63661977236758134f * fast_atan(z);
        if (si != si) si = 0.0f;                        // remove_nan
        res[j] = si;
    }

    *(float4*)(out + (size_t)b * (H_ * W_) + h * W_ + w) =
        make_float4(res[0], res[1], res[2], res[3]);
}

extern "C" void kernel_launch(void* const* d_in, const int* in_sizes, int n_in,
                              void* d_out, int out_size, void* d_ws, size_t ws_size,
                              hipStream_t stream) {
    const float* x = (const float*)d_in[0];
    float* out = (float*)d_out;
    dim3 grid(H_, B_);
    dim3 block(384);
    ShapeIndex_kernel<<<grid, block, 0, stream>>>(x, out);
}

// Round 3
// 276.823 us; speedup vs baseline: 1.0726x; 1.0260x over previous
//
#include <hip/hip_runtime.h>
#include <cmath>

// Problem constants from the reference: x is (16, 1, 1536, 1536) float32.
#define B_ 16
#define H_ 1536
#define W_ 1536

typedef float v4f __attribute__((ext_vector_type(4)));

// NUMERICS CONTRACT (do not relax): everything through `root` must be
// bitwise identical to the numpy f32 reference -- the discriminant
// Hc^2-Kc is analytically >=0; its rounding-determined sign selects
// between si=0 (NaN path) and si~=+-1, a jump of 1.0. Hence: exact
// reference association, IEEE scalar div/sqrt, contract(off). The v4f
// vector ops below lower to v_pk_{add,mul}_f32 which round identically
// to scalar v_{add,mul}_f32 per half -- packing is a pure issue-slot win.
//
// Dropped-check justifications (output-equivalent for finite inputs):
//  * remove_nan(Hc): denom 2*sqrt(cube) >= 2 (one_pq >= 1), A finite
//    for N(0,1) inputs -> Hc never NaN.
//  * remove_nan(Kc): denom sq >= 1, numerator finite -> never NaN.
//  * remove_nan(kmin/kmax): NaN iff root is NaN; reference then yields
//    num=den=0 -> z=NaN -> si=0; propagating the NaN yields z=NaN -> si=0.
__global__ __launch_bounds__(384) void ShapeIndex_kernel(
        const float* __restrict__ x, float* __restrict__ out) {
#pragma clang fp contract(off)
    const int h  = blockIdx.x;       // 0..1535
    const int b  = blockIdx.y;       // 0..15
    const int w  = threadIdx.x * 4;

    const float* plane = x + (size_t)b * (H_ * W_);
    const int hm1 = (h == 0) ? (H_ - 1) : (h - 1);
    const int hm2 = (h <= 1) ? (h + H_ - 2) : (h - 2);

    const float4 vc = *(const float4*)(plane + h   * W_ + w);  // x[h][w..w+3]
    const float4 v1 = *(const float4*)(plane + hm1 * W_ + w);  // x[h-1][...]
    const float4 v2 = *(const float4*)(plane + hm2 * W_ + w);  // x[h-2][...]

    const int wm1 = (w == 0) ? (W_ - 1) : (w - 1);
    const int wm2 = (w == 0) ? (W_ - 2) : (w - 2);
    const float L0  = plane[h   * W_ + wm1];  // x[h][w-1]
    const float L1  = plane[h   * W_ + wm2];  // x[h][w-2]
    const float Lh1 = plane[hm1 * W_ + wm1];  // x[h-1][w-1]

    const v4f xc    = {vc.x, vc.y, vc.z, vc.w};
    const v4f xh1   = {v1.x, v1.y, v1.z, v1.w};
    const v4f xh2   = {v2.x, v2.y, v2.z, v2.w};
    const v4f xw1   = {L0,  vc.x, vc.y, vc.z};   // x[h][w-1] per element
    const v4f xw2   = {L1,  L0,  vc.x, vc.y};    // x[h][w-2] per element
    const v4f xh1w1 = {Lh1, v1.x, v1.y, v1.z};   // x[h-1][w-1] per element

    // grad(m, ax) = roll(m,1,ax) - m : single f32 subs, reference order.
    const v4f p    = xh1   - xc;
    const v4f q    = xw1   - xc;
    const v4f p_up = xh2   - xh1;
    const v4f p_lf = xh1w1 - xw1;
    const v4f q_lf = xw2   - xw1;
    const v4f r = p_up - p;
    const v4f s = p_lf - p;
    const v4f t = q_lf - q;

    const v4f pp = p * p;
    const v4f qq = q * q;
    const v4f one_pq = (1.0f + pp) + qq;               // (1.0 + p*p) + q*q
    // ((1+q*q)*r - 2.0*p*q*s) + (1+p*p)*t, left-to-right like Python
    const v4f A = ((1.0f + qq) * r - ((2.0f * p) * q) * s) + (1.0f + pp) * t;
    const v4f sq   = one_pq * one_pq;                  // one_pq ** 2
    const v4f cube = sq * one_pq;                      // one_pq ** 3
    const v4f numk = r * t - s * s;

    // Scalar IEEE div/sqrt (must be correctly rounded; no packed variant).
    v4f Hc, Kc;
#pragma unroll
    for (int j = 0; j < 4; ++j) {
        Hc[j] = -(A[j] / (2.0f * __builtin_sqrtf(cube[j])));
        Kc[j] = numk[j] / sq[j];
    }

    const v4f disc = Hc * Hc - Kc;                     // sign is critical
    v4f root;
#pragma unroll
    for (int j = 0; j < 4; ++j) root[j] = __builtin_sqrtf(disc[j]); // NaN if <0

    const v4f kmin = Hc - root;   // NaN propagates (equivalent to ref, see top)
    const v4f kmax = Hc + root;
    const v4f num  = kmax + kmin;
    const v4f den  = kmax - kmin;

    // z = num/den via num*rcp(den): den=0 -> +-inf (num!=0) or NaN (num==0);
    // NaN den -> NaN. Matches IEEE special cases; ~1ulp finite error lands in
    // atan's smooth/saturating region (verified: absmax identical to libm).
    v4f z;
#pragma unroll
    for (int j = 0; j < 4; ++j) z[j] = num[j] * __builtin_amdgcn_rcpf(den[j]);

    // fast atan, ~1e-5 rad: atan(x)=pi/2-atan(1/x) for |x|>1; rcp(inf)=0
    // gives exact +-pi/2 saturation; NaN>1 false -> NaN propagates via poly.
    v4f u;
    bool big[4];
#pragma unroll
    for (int j = 0; j < 4; ++j) {
        const float az  = __builtin_fabsf(z[j]);
        const float inv = __builtin_amdgcn_rcpf(az);
        big[j] = az > 1.0f;
        u[j]   = big[j] ? inv : az;
    }
    const v4f x2 = u * u;
    const v4f C5 = -0.01172120f, C4 = 0.05265332f, C3 = -0.11643287f,
              C2 = 0.19354346f,  C1 = -0.33262347f, C0 = 0.99997726f;
    v4f pl = __builtin_elementwise_fma(x2, C5, C4);
    pl = __builtin_elementwise_fma(x2, pl, C3);
    pl = __builtin_elementwise_fma(x2, pl, C2);
    pl = __builtin_elementwise_fma(x2, pl, C1);
    pl = __builtin_elementwise_fma(x2, pl, C0);
    const v4f a    = u * pl;
    const v4f asub = 1.57079632679489662f - a;

    v4f rs;
#pragma unroll
    for (int j = 0; j < 4; ++j)
        rs[j] = __builtin_copysignf(big[j] ? asub[j] : a[j], z[j]);
    const v4f siv = 0.63661977236758134f * rs;

    float res[4];
#pragma unroll
    for (int j = 0; j < 4; ++j)
        res[j] = (siv[j] == siv[j]) ? siv[j] : 0.0f;   // remove_nan

    *(float4*)(out + (size_t)b * (H_ * W_) + h * W_ + w) =
        make_float4(res[0], res[1], res[2], res[3]);
}

extern "C" void kernel_launch(void* const* d_in, const int* in_sizes, int n_in,
                              void* d_out, int out_size, void* d_ws, size_t ws_size,
                              hipStream_t stream) {
    const float* x = (const float*)d_in[0];
    float* out = (float*)d_out;
    dim3 grid(H_, B_);
    dim3 block(384);
    ShapeIndex_kernel<<<grid, block, 0, stream>>>(x, out);
}